// Round 10
// baseline (380.513 us; speedup 1.0000x reference)
//
#include <hip/hip_runtime.h>
#include <cmath>

#define H_ 256
#define W_ 256
#define NB 256           // zmin buckets
#define BANDSH 3         // log2(band height): 8-row bands
#define NBAND (H_ >> BANDSH)   // 32
#define ILV 4            // face-subset waves per tile block
#define INITKEY 0x7f800000FFFFFFFFull

__device__ inline unsigned fkey(float f) {
  unsigned u = __float_as_uint(f);
  return (u & 0x80000000u) ? ~u : (u | 0x80000000u);
}
__device__ inline float unfkey(unsigned k) {
  return (k & 0x80000000u) ? __uint_as_float(k & 0x7fffffffu) : __uint_as_float(~k);
}

__device__ inline int zbucket(float zmin, float zlo, float scale) {
  int bkt = 0;
  if (zmin == zmin) bkt = min(NB - 1, max(0, (int)((zmin - zlo) * scale)));
  return bkt;
}

// ---------------- transform (+ vertex-z minmax for bucket range) ----------------
__global__ void k_transform(const float* __restrict__ verts, const float* __restrict__ Km,
                            const float* __restrict__ Rt, float* __restrict__ vpix,
                            unsigned* __restrict__ minmax, int B, int V) {
  int i = blockIdx.x * blockDim.x + threadIdx.x;
  unsigned kmin = 0xFFFFFFFFu, kmax = 0u;
  if (i < B * V) {
    int b = i / V;
    float x = verts[(size_t)i * 3 + 0], y = verts[(size_t)i * 3 + 1], z = verts[(size_t)i * 3 + 2];
    const float* R = Rt + (size_t)b * 12;
    float cx = __fadd_rn(__fadd_rn(__fadd_rn(__fmul_rn(R[0], x), __fmul_rn(R[1], y)), __fmul_rn(R[2], z)), R[3]);
    float cy = __fadd_rn(__fadd_rn(__fadd_rn(__fmul_rn(R[4], x), __fmul_rn(R[5], y)), __fmul_rn(R[6], z)), R[7]);
    float cz = __fadd_rn(__fadd_rn(__fadd_rn(__fmul_rn(R[8], x), __fmul_rn(R[9], y)), __fmul_rn(R[10], z)), R[11]);
    const float* Kb = Km + (size_t)b * 9;
    float px = __fadd_rn(__fadd_rn(__fmul_rn(Kb[0], cx), __fmul_rn(Kb[1], cy)), __fmul_rn(Kb[2], cz));
    float py = __fadd_rn(__fadd_rn(__fmul_rn(Kb[3], cx), __fmul_rn(Kb[4], cy)), __fmul_rn(Kb[5], cz));
    vpix[(size_t)i * 3 + 0] = __fdiv_rn(px, cz);
    vpix[(size_t)i * 3 + 1] = __fdiv_rn(py, cz);
    vpix[(size_t)i * 3 + 2] = cz;
    if (minmax && cz == cz) { kmin = fkey(cz); kmax = kmin; }
  }
  if (minmax) {
    #pragma unroll
    for (int m = 32; m >= 1; m >>= 1) {
      kmin = min(kmin, (unsigned)__shfl_xor((int)kmin, m));
      kmax = max(kmax, (unsigned)__shfl_xor((int)kmax, m));
    }
    if ((threadIdx.x & 63) == 0) {
      atomicMin(&minmax[0], kmin);
      atomicMax(&minmax[1], kmax);
    }
  }
}

// ---------------- init (runs before transform: minmax must be ready) ----------------
__global__ void k_init(int* __restrict__ cnt, int* __restrict__ bcur, int n,
                       unsigned* __restrict__ minmax) {
  int i = blockIdx.x * blockDim.x + threadIdx.x;
  if (i < n) { cnt[i] = 0; bcur[i] = 0; }
  if (i == 0) { minmax[0] = 0xFFFFFFFFu; minmax[1] = 0u; }
}

// ---------------- per-face precompute + fused band-bucket hist ----------------
// meta = {zmin, packbits(segmask|ylo<<8|yhi<<16), bkt_bits, floorval}; invalid: pack=0
__global__ void k_faceprep(const float* __restrict__ vpix, const int* __restrict__ vi,
                           const int* __restrict__ vti, const float* __restrict__ vt,
                           float4* __restrict__ sA, float4* __restrict__ sB4,
                           float4* __restrict__ sC, float4* __restrict__ sZ1,
                           float4* __restrict__ sE1, float4* __restrict__ sE2,
                           float4* __restrict__ sUV12, float4* __restrict__ sUV2,
                           float4* __restrict__ meta, const unsigned* __restrict__ minmax,
                           int* __restrict__ cnt, int B, int V, int F) {
  int i = blockIdx.x * blockDim.x + threadIdx.x;
  if (i >= B * F) return;
  int b = i / F, f = i - b * F;
  int i0 = vi[f * 3 + 0], i1 = vi[f * 3 + 1], i2 = vi[f * 3 + 2];
  const float* base = vpix + (size_t)b * V * 3;
  float ax = base[(size_t)i0 * 3], ay = base[(size_t)i0 * 3 + 1], az = base[(size_t)i0 * 3 + 2];
  float bx = base[(size_t)i1 * 3], by = base[(size_t)i1 * 3 + 1], bz = base[(size_t)i1 * 3 + 2];
  float cx = base[(size_t)i2 * 3], cy = base[(size_t)i2 * 3 + 1], cz = base[(size_t)i2 * 3 + 2];
  float e0x = __fsub_rn(cx, bx), e0y = __fsub_rn(cy, by);
  float e1x = __fsub_rn(ax, cx), e1y = __fsub_rn(ay, cy);
  float e2x = __fsub_rn(bx, ax), e2y = __fsub_rn(by, ay);
  float area = __fsub_rn(__fmul_rn(e2x, __fsub_rn(cy, ay)), __fmul_rn(e2y, __fsub_rn(cx, ax)));
  float s = (area > 0.f) ? 1.f : ((area < 0.f) ? -1.f : 0.f);
  bool nz = fabsf(area) > 1e-8f;
  bool zv = (az > 0.f) && (bz > 0.f) && (cz > 0.f);
  float sp = (nz && zv) ? s : __uint_as_float(0x7fc00000u);  // NaN: invalid
  float ar = nz ? area : 1.0f;
  float zmin = fminf(az, fminf(bz, cz));
  // raster records (sp-prefolded edges: IEEE-exact for sp=+-1; NaN -> inside=false)
  sA[i]  = make_float4(ax, ay, bx, by);
  sB4[i] = make_float4(cx, cy, __fmul_rn(sp, e0x), __fmul_rn(sp, e0y));
  sC[i]  = make_float4(__fmul_rn(sp, e1x), __fmul_rn(sp, e1y),
                       __fmul_rn(sp, e2x), __fmul_rn(sp, e2y));
  sZ1[i] = make_float4(az, bz, cz, __fmul_rn(sp, ar));
  // render records (RAW edges — identical bits to inline recompute)
  sE1[i] = make_float4(cx, cy, e0x, e0y);
  sE2[i] = make_float4(e1x, e1y, e2x, e2y);
  int t0 = vti[f * 3], t1 = vti[f * 3 + 1], t2 = vti[f * 3 + 2];
  float u0x = __fsub_rn(__fmul_rn(vt[(size_t)t0 * 2], 2.f), 1.f);
  float u0y = __fsub_rn(__fmul_rn(vt[(size_t)t0 * 2 + 1], 2.f), 1.f);
  float u1x = __fsub_rn(__fmul_rn(vt[(size_t)t1 * 2], 2.f), 1.f);
  float u1y = __fsub_rn(__fmul_rn(vt[(size_t)t1 * 2 + 1], 2.f), 1.f);
  float u2x = __fsub_rn(__fmul_rn(vt[(size_t)t2 * 2], 2.f), 1.f);
  float u2y = __fsub_rn(__fmul_rn(vt[(size_t)t2 * 2 + 1], 2.f), 1.f);
  sUV12[i] = make_float4(u0x, u0y, u1x, u1y);
  sUV2[i]  = make_float4(u2x, u2y, 0.f, 0.f);
  // integer pixel bbox (conservative-exact at pixel centers) -> packed cull word
  unsigned pack = 0u;   // 0 = invalid (empty segmask)
  int bkt = 0; float floorval = 0.f;
  float zlo = unfkey(minmax[0]), zhi = unfkey(minmax[1]);
  float rng = fmaxf(zhi - zlo, 1e-12f);
  float scale = (float)NB / rng;
  if (sp == sp) {
    float minx = fminf(ax, fminf(bx, cx)), maxx = fmaxf(ax, fmaxf(bx, cx));
    float miny = fminf(ay, fminf(by, cy)), maxy = fmaxf(ay, fmaxf(by, cy));
    int xl = (int)ceilf(fmaxf(fminf(minx - 0.5f, 1e9f), -1e9f));
    int xh = (int)floorf(fmaxf(fminf(maxx - 0.5f, 1e9f), -1e9f));
    int yl = (int)ceilf(fmaxf(fminf(miny - 0.5f, 1e9f), -1e9f));
    int yh = (int)floorf(fmaxf(fminf(maxy - 0.5f, 1e9f), -1e9f));
    if (!(xl > xh || yl > yh || xh < 0 || xl > W_ - 1 || yh < 0 || yl > H_ - 1)) {
      int xlo = max(xl, 0), xhi = min(xh, W_ - 1);
      int ylo = max(yl, 0), yhi = min(yh, H_ - 1);
      unsigned segmask = (((1u << ((xhi >> 6) + 1)) - 1u) & ~((1u << (xlo >> 6)) - 1u)) & 0xFu;
      pack = segmask | ((unsigned)ylo << 8) | ((unsigned)yhi << 16);
      bkt = zbucket(zmin, zlo, scale);
      floorval = zlo + (float)bkt * (rng / (float)NB);
      for (int band = (ylo >> BANDSH); band <= (yhi >> BANDSH); ++band)
        atomicAdd(&cnt[(b * NBAND + band) * NB + bkt], 1);
    }
  }
  meta[i] = make_float4(zmin, __uint_as_float(pack), __int_as_float(bkt), floorval);
}

// per-(band) exclusive prefix over buckets; bstart[row][NB] = total length
__global__ void k_bandscan(const int* __restrict__ cnt, int* __restrict__ bstart) {
  __shared__ int sh[NB];
  int rowi = blockIdx.x;
  int t = threadIdx.x;
  sh[t] = cnt[rowi * NB + t];
  __syncthreads();
  int self = sh[t];
  for (int ofs = 1; ofs < NB; ofs <<= 1) {
    int u = (t >= ofs) ? sh[t - ofs] : 0;
    __syncthreads();
    sh[t] += u;
    __syncthreads();
  }
  bstart[rowi * (NB + 1) + t] = sh[t] - self;
  if (t == NB - 1) bstart[rowi * (NB + 1) + NB] = sh[t];
}

// ---------------- fill band lists: entry = {pack, fid, zmin, zfloor} ----------------
__global__ void k_scatter(const float4* __restrict__ meta,
                          const int* __restrict__ bstart, int* __restrict__ bcur,
                          uint4* __restrict__ list, int B, int F) {
  int i = blockIdx.x * blockDim.x + threadIdx.x;
  if (i >= B * F) return;
  int b = i / F, f = i - b * F;
  float4 m = meta[i];
  unsigned pack = __float_as_uint(m.y);
  if ((pack & 0xFu) == 0u) return;  // invalid / off-screen
  int bkt = __float_as_int(m.z);
  uint4 ent = make_uint4(pack, (unsigned)f, __float_as_uint(m.x), __float_as_uint(m.w));
  int ylo = (int)((pack >> 8) & 255u), yhi = (int)((pack >> 16) & 255u);
  for (int band = (ylo >> BANDSH); band <= (yhi >> BANDSH); ++band) {
    int rowi = b * NBAND + band;
    int slot = bstart[rowi * (NB + 1) + bkt] + atomicAdd(&bcur[rowi * NB + bkt], 1);
    list[(size_t)rowi * F + slot] = ent;
  }
}

// ---------------- band rasterizer (R9 structure + 2-deep meta prefetch) ----------------
__global__ __launch_bounds__(64 * ILV) void k_raster_band(const uint4* __restrict__ list,
                                                          const int* __restrict__ bstart,
                                                          const float4* __restrict__ sA,
                                                          const float4* __restrict__ sB4,
                                                          const float4* __restrict__ sC,
                                                          const float4* __restrict__ sZ1,
                                                          float* __restrict__ o_idx,
                                                          int B, int F) {
  int seg = blockIdx.x;
  int y   = blockIdx.y;
  int b   = blockIdx.z;
  int tid = threadIdx.x;
  int w = tid >> 6, lane = tid & 63;
  __shared__ unsigned long long sk[64];
  if (tid < 64) sk[tid] = INITKEY;
  __syncthreads();
  int rowi = b * NBAND + (y >> BANDSH);
  int len = bstart[rowi * (NB + 1) + NB];
  const uint4* L = list + (size_t)rowi * F;
  size_t fb = (size_t)b * F;
  float px = seg * 64 + lane + 0.5f, py = y + 0.5f;
  unsigned long long bestkey = INITKEY;
  float bestz = INFINITY;
  int it = 0;
  int pos = w;
  // 2-deep software pipeline on the 16B meta entry (issue-to-use > L2 latency)
  uint4 eA = (pos < len) ? L[pos] : make_uint4(0u, 0u, 0u, 0x7f800000u);
  uint4 eB = (pos + ILV < len) ? L[pos + ILV] : eA;
  while (pos < len) {
    int q2 = pos + 2 * ILV;
    uint4 eC = L[(q2 < len) ? q2 : (len - 1)];  // prefetch 2 iterations ahead
    // scalarize the wave-uniform entry -> scalar branches, scalar record loads
    unsigned pack = __builtin_amdgcn_readfirstlane(eA.x);
    int      fid  = __builtin_amdgcn_readfirstlane((int)eA.y);
    float    zmn  = __uint_as_float(__builtin_amdgcn_readfirstlane(eA.z));
    float    zfl  = __uint_as_float(__builtin_amdgcn_readfirstlane(eA.w));
    // break: bucket floor lower-bounds zmin of this and all later entries (bucket-ascending)
    float floor0 = __fmul_rn(zfl, 0.9999f) - 1e-5f;  // margin: never skips a tie
    if (__all(floor0 > bestz)) break;
    ++it;
    if ((it & 7) == 0) {  // periodic cross-wave exchange via LDS
      unsigned long long old = atomicMin(&sk[lane], bestkey);
      if (old < bestkey) { bestkey = old; bestz = __uint_as_float((unsigned)(bestkey >> 32)); }
    }
    bool cull = !((pack >> seg) & 1u) ||
                (y < (int)((pack >> 8) & 255u)) || (y > (int)((pack >> 16) & 255u));
    if (!cull) {
      float4 a0 = sA[fb + fid];
      float4 a1 = sB4[fb + fid];
      float4 a2 = sC[fb + fid];
      // t_i == w_i * sp bit-exactly (sp pre-folded; -0>=0 true, NaN false)
      float t0 = __fsub_rn(__fmul_rn(a1.z, __fsub_rn(py, a0.w)), __fmul_rn(a1.w, __fsub_rn(px, a0.z)));
      float t1 = __fsub_rn(__fmul_rn(a2.x, __fsub_rn(py, a1.y)), __fmul_rn(a2.y, __fsub_rn(px, a1.x)));
      float t2 = __fsub_rn(__fmul_rn(a2.z, __fsub_rn(py, a0.y)), __fmul_rn(a2.w, __fsub_rn(px, a0.x)));
      bool inside = (t0 >= 0.f) && (t1 >= 0.f) && (t2 >= 0.f);
      // divide-skip: zmin*0.9999 > bestz provably can't beat or tie
      if (inside && !(__fmul_rn(zmn, 0.9999f) > bestz)) {
        float4 zz = sZ1[fb + fid];   // rare path only
        float u0 = __fdiv_rn(__fdiv_rn(t0, zz.w), zz.x);
        float u1 = __fdiv_rn(__fdiv_rn(t1, zz.w), zz.y);
        float u2 = __fdiv_rn(__fdiv_rn(t2, zz.w), zz.z);
        float invz = __fadd_rn(__fadd_rn(u0, u1), u2);
        if (invz > 0.f) {
          float z = __fdiv_rn(1.0f, fmaxf(invz, 1e-12f));
          unsigned long long ck = ((unsigned long long)__float_as_uint(z) << 32) | (unsigned)fid;
          if (ck < bestkey) {
            bestkey = ck; bestz = z;
            atomicMin(&sk[lane], ck);  // push so other waves see it
          }
        }
      }
    }
    pos += ILV;
    eA = eB; eB = eC;
  }
  atomicMin(&sk[lane], bestkey);
  __syncthreads();
  if (tid < 64) {
    unsigned long long k = sk[tid];
    unsigned zb = (unsigned)(k >> 32);
    o_idx[(size_t)b * (H_ * W_) + (size_t)y * W_ + seg * 64 + tid] =
        (zb >= 0x7f800000u) ? -1.0f : (float)(int)(unsigned)(k & 0xffffffffu);
  }
}

// ---------------- last-resort rasterizer (no workspace) ----------------
__global__ void k_raster_direct(const float* __restrict__ vpix, const int* __restrict__ vi,
                                float* __restrict__ idxout, int B, int V, int F) {
  int p = blockIdx.x * blockDim.x + threadIdx.x;
  if (p >= B * H_ * W_) return;
  int b = p / (H_ * W_); int pid = p - b * (H_ * W_);
  float px = (pid & (W_ - 1)) + 0.5f, py = (pid >> 8) + 0.5f;
  const float* base = vpix + (size_t)b * V * 3;
  float bestz = INFINITY; int besti = -1;
  for (int f = 0; f < F; ++f) {
    int i0 = vi[f * 3], i1 = vi[f * 3 + 1], i2 = vi[f * 3 + 2];
    float ax = base[(size_t)i0 * 3], ay = base[(size_t)i0 * 3 + 1], za = base[(size_t)i0 * 3 + 2];
    float bx = base[(size_t)i1 * 3], by = base[(size_t)i1 * 3 + 1], zb = base[(size_t)i1 * 3 + 2];
    float cx = base[(size_t)i2 * 3], cy = base[(size_t)i2 * 3 + 1], zc = base[(size_t)i2 * 3 + 2];
    float e0x = __fsub_rn(cx, bx), e0y = __fsub_rn(cy, by);
    float e1x = __fsub_rn(ax, cx), e1y = __fsub_rn(ay, cy);
    float e2x = __fsub_rn(bx, ax), e2y = __fsub_rn(by, ay);
    float area = __fsub_rn(__fmul_rn(e2x, __fsub_rn(cy, ay)), __fmul_rn(e2y, __fsub_rn(cx, ax)));
    float s = (area > 0.f) ? 1.f : ((area < 0.f) ? -1.f : 0.f);
    bool nz = fabsf(area) > 1e-8f;
    bool zv = (za > 0.f) && (zb > 0.f) && (zc > 0.f);
    float sp = (nz && zv) ? s : __uint_as_float(0x7fc00000u);
    float ar = nz ? area : 1.0f;
    float w0 = __fsub_rn(__fmul_rn(e0x, __fsub_rn(py, by)), __fmul_rn(e0y, __fsub_rn(px, bx)));
    float w1 = __fsub_rn(__fmul_rn(e1x, __fsub_rn(py, cy)), __fmul_rn(e1y, __fsub_rn(px, cx)));
    float w2 = __fsub_rn(__fmul_rn(e2x, __fsub_rn(py, ay)), __fmul_rn(e2y, __fsub_rn(px, ax)));
    bool inside = (__fmul_rn(w0, sp) >= 0.f) && (__fmul_rn(w1, sp) >= 0.f) && (__fmul_rn(w2, sp) >= 0.f);
    if (inside) {
      float invz = __fadd_rn(__fadd_rn(__fdiv_rn(__fdiv_rn(w0, ar), za),
                                       __fdiv_rn(__fdiv_rn(w1, ar), zb)),
                             __fdiv_rn(__fdiv_rn(w2, ar), zc));
      if (invz > 0.f) {
        float z = __fdiv_rn(1.0f, fmaxf(invz, 1e-12f));
        if (z < bestz) { bestz = z; besti = f; }
      }
    }
  }
  idxout[p] = (float)besti;
}

// ---------------- render from face records (6 float4 gathers + tex) ----------------
__global__ __launch_bounds__(256) void k_render_rec(const float4* __restrict__ sA,
                                                    const float4* __restrict__ sE1,
                                                    const float4* __restrict__ sE2,
                                                    const float4* __restrict__ sZ1,
                                                    const float4* __restrict__ sUV12,
                                                    const float4* __restrict__ sUV2,
                                                    const float* __restrict__ tex,
                                                    const float* __restrict__ idxin,
                                                    float* __restrict__ o_img, float* __restrict__ o_depth,
                                                    float* __restrict__ o_vt, float* __restrict__ o_bary,
                                                    float* __restrict__ o_mask,
                                                    int B, int F, int TH, int TW) {
  int p = blockIdx.x * blockDim.x + threadIdx.x;
  if (p >= B * H_ * W_) return;
  int HW = H_ * W_;
  int b = p / HW; int pid = p - b * HW;
  int y = pid >> 8, x = pid & (W_ - 1);
  int idx = (int)idxin[p];
  size_t pix2 = (size_t)b * 2 * HW + pid;
  size_t pix3 = (size_t)b * 3 * HW + pid;
  if (idx < 0) {
    o_depth[p] = 0.f; o_mask[p] = 0.f;
    o_vt[pix2] = 0.f; o_vt[pix2 + HW] = 0.f;
    o_bary[pix3] = 0.f; o_bary[pix3 + HW] = 0.f; o_bary[pix3 + 2 * HW] = 0.f;
    o_img[pix3] = 0.f; o_img[pix3 + HW] = 0.f; o_img[pix3 + 2 * HW] = 0.f;
    return;
  }
  size_t gp = (size_t)b * F + idx;
  float4 a0 = sA[gp];    // ax,ay,bx,by
  float4 e1 = sE1[gp];   // cx,cy,e0x,e0y (raw)
  float4 e2 = sE2[gp];   // e1x,e1y,e2x,e2y (raw)
  float4 zz = sZ1[gp];   // az,bz,cz,-
  float4 uv = sUV12[gp];
  float4 uv2 = sUV2[gp];
  float ptx = x + 0.5f, pty = y + 0.5f;
  float w0 = __fsub_rn(__fmul_rn(e1.z, __fsub_rn(pty, a0.w)), __fmul_rn(e1.w, __fsub_rn(ptx, a0.z)));
  float w1 = __fsub_rn(__fmul_rn(e2.x, __fsub_rn(pty, e1.y)), __fmul_rn(e2.y, __fsub_rn(ptx, e1.x)));
  float w2 = __fsub_rn(__fmul_rn(e2.z, __fsub_rn(pty, a0.y)), __fmul_rn(e2.w, __fsub_rn(ptx, a0.x)));
  float area = __fadd_rn(__fadd_rn(w0, w1), w2);
  float ar = (fabsf(area) > 1e-8f) ? area : 1.0f;
  float f0 = __fdiv_rn(__fdiv_rn(w0, ar), fmaxf(zz.x, 1e-8f));
  float f1 = __fdiv_rn(__fdiv_rn(w1, ar), fmaxf(zz.y, 1e-8f));
  float f2 = __fdiv_rn(__fdiv_rn(w2, ar), fmaxf(zz.z, 1e-8f));
  float invz = __fadd_rn(__fadd_rn(f0, f1), f2);
  float invz_s = (fabsf(invz) > 1e-12f) ? invz : 1.0f;
  float depth = __fdiv_rn(1.0f, invz_s);
  float bary0 = __fdiv_rn(f0, invz_s);
  float bary1 = __fdiv_rn(f1, invz_s);
  float bary2 = __fdiv_rn(f2, invz_s);
  o_depth[p] = depth; o_mask[p] = 1.0f;
  o_bary[pix3] = bary0; o_bary[pix3 + HW] = bary1; o_bary[pix3 + 2 * HW] = bary2;
  float gx = __fadd_rn(__fadd_rn(__fmul_rn(uv.x, bary0), __fmul_rn(uv.z, bary1)), __fmul_rn(uv2.x, bary2));
  float gy = __fadd_rn(__fadd_rn(__fmul_rn(uv.y, bary0), __fmul_rn(uv.w, bary1)), __fmul_rn(uv2.y, bary2));
  o_vt[pix2] = gx; o_vt[pix2 + HW] = gy;
  float sx = __fsub_rn(__fdiv_rn(__fmul_rn(__fadd_rn(gx, 1.0f), (float)TW), 2.0f), 0.5f);
  float sy = __fsub_rn(__fdiv_rn(__fmul_rn(__fadd_rn(gy, 1.0f), (float)TH), 2.0f), 0.5f);
  float x0f = floorf(sx), y0f = floorf(sy);
  float wx = __fsub_rn(sx, x0f), wy = __fsub_rn(sy, y0f);
  float omx = __fsub_rn(1.0f, wx), omy = __fsub_rn(1.0f, wy);
  int x0 = (int)x0f, y0 = (int)y0f;
  int x1 = x0 + 1, y1 = y0 + 1;
  bool v00 = (x0 >= 0) && (x0 < TW) && (y0 >= 0) && (y0 < TH);
  bool v10 = (x1 >= 0) && (x1 < TW) && (y0 >= 0) && (y0 < TH);
  bool v01 = (x0 >= 0) && (x0 < TW) && (y1 >= 0) && (y1 < TH);
  bool v11 = (x1 >= 0) && (x1 < TW) && (y1 >= 0) && (y1 < TH);
  int x0c = min(max(x0, 0), TW - 1), x1c = min(max(x1, 0), TW - 1);
  int y0c = min(max(y0, 0), TH - 1), y1c = min(max(y1, 0), TH - 1);
  const float* tb = tex + (size_t)b * 3 * TH * TW;
  #pragma unroll
  for (int ch = 0; ch < 3; ++ch) {
    const float* tc = tb + (size_t)ch * TH * TW;
    float g00 = v00 ? tc[(size_t)y0c * TW + x0c] : 0.f;
    float g10 = v10 ? tc[(size_t)y0c * TW + x1c] : 0.f;
    float g01 = v01 ? tc[(size_t)y1c * TW + x0c] : 0.f;
    float g11 = v11 ? tc[(size_t)y1c * TW + x1c] : 0.f;
    float r = __fmul_rn(__fmul_rn(g00, omx), omy);
    r = __fadd_rn(r, __fmul_rn(__fmul_rn(g10, wx), omy));
    r = __fadd_rn(r, __fmul_rn(__fmul_rn(g01, omx), wy));
    r = __fadd_rn(r, __fmul_rn(__fmul_rn(g11, wx), wy));
    o_img[pix3 + (size_t)ch * HW] = r;
  }
}

// ---------------- fallback render (per-pixel gathers, no records) ----------------
__global__ __launch_bounds__(256) void k_render(const float* __restrict__ vpix, const int* __restrict__ vi,
                                                const int* __restrict__ vti, const float* __restrict__ vt,
                                                const float* __restrict__ tex, const float* __restrict__ idxin,
                                                float* __restrict__ o_img, float* __restrict__ o_depth,
                                                float* __restrict__ o_vt, float* __restrict__ o_bary,
                                                float* __restrict__ o_mask,
                                                int B, int V, int F, int TH, int TW) {
  int p = blockIdx.x * blockDim.x + threadIdx.x;
  if (p >= B * H_ * W_) return;
  int HW = H_ * W_;
  int b = p / HW; int pid = p - b * HW;
  int y = pid >> 8, x = pid & (W_ - 1);
  int idx = (int)idxin[p];
  size_t pix2 = (size_t)b * 2 * HW + pid;
  size_t pix3 = (size_t)b * 3 * HW + pid;
  if (idx < 0) {
    o_depth[p] = 0.f; o_mask[p] = 0.f;
    o_vt[pix2] = 0.f; o_vt[pix2 + HW] = 0.f;
    o_bary[pix3] = 0.f; o_bary[pix3 + HW] = 0.f; o_bary[pix3 + 2 * HW] = 0.f;
    o_img[pix3] = 0.f; o_img[pix3 + HW] = 0.f; o_img[pix3 + 2 * HW] = 0.f;
    return;
  }
  const float* base = vpix + (size_t)b * V * 3;
  int i0 = vi[idx * 3], i1 = vi[idx * 3 + 1], i2 = vi[idx * 3 + 2];
  float ax = base[(size_t)i0 * 3], ay = base[(size_t)i0 * 3 + 1], az = base[(size_t)i0 * 3 + 2];
  float bx = base[(size_t)i1 * 3], by = base[(size_t)i1 * 3 + 1], bz = base[(size_t)i1 * 3 + 2];
  float cx = base[(size_t)i2 * 3], cy = base[(size_t)i2 * 3 + 1], cz = base[(size_t)i2 * 3 + 2];
  float ptx = x + 0.5f, pty = y + 0.5f;
  float w0 = __fsub_rn(__fmul_rn(__fsub_rn(cx, bx), __fsub_rn(pty, by)),
                       __fmul_rn(__fsub_rn(cy, by), __fsub_rn(ptx, bx)));
  float w1 = __fsub_rn(__fmul_rn(__fsub_rn(ax, cx), __fsub_rn(pty, cy)),
                       __fmul_rn(__fsub_rn(ay, cy), __fsub_rn(ptx, cx)));
  float w2 = __fsub_rn(__fmul_rn(__fsub_rn(bx, ax), __fsub_rn(pty, ay)),
                       __fmul_rn(__fsub_rn(by, ay), __fsub_rn(ptx, ax)));
  float area = __fadd_rn(__fadd_rn(w0, w1), w2);
  float ar = (fabsf(area) > 1e-8f) ? area : 1.0f;
  float f0 = __fdiv_rn(__fdiv_rn(w0, ar), fmaxf(az, 1e-8f));
  float f1 = __fdiv_rn(__fdiv_rn(w1, ar), fmaxf(bz, 1e-8f));
  float f2 = __fdiv_rn(__fdiv_rn(w2, ar), fmaxf(cz, 1e-8f));
  float invz = __fadd_rn(__fadd_rn(f0, f1), f2);
  float invz_s = (fabsf(invz) > 1e-12f) ? invz : 1.0f;
  float depth = __fdiv_rn(1.0f, invz_s);
  float bary0 = __fdiv_rn(f0, invz_s);
  float bary1 = __fdiv_rn(f1, invz_s);
  float bary2 = __fdiv_rn(f2, invz_s);
  o_depth[p] = depth; o_mask[p] = 1.0f;
  o_bary[pix3] = bary0; o_bary[pix3 + HW] = bary1; o_bary[pix3 + 2 * HW] = bary2;
  int t0 = vti[idx * 3], t1 = vti[idx * 3 + 1], t2 = vti[idx * 3 + 2];
  float u0x = __fsub_rn(__fmul_rn(vt[(size_t)t0 * 2], 2.f), 1.f);
  float u0y = __fsub_rn(__fmul_rn(vt[(size_t)t0 * 2 + 1], 2.f), 1.f);
  float u1x = __fsub_rn(__fmul_rn(vt[(size_t)t1 * 2], 2.f), 1.f);
  float u1y = __fsub_rn(__fmul_rn(vt[(size_t)t1 * 2 + 1], 2.f), 1.f);
  float u2x = __fsub_rn(__fmul_rn(vt[(size_t)t2 * 2], 2.f), 1.f);
  float u2y = __fsub_rn(__fmul_rn(vt[(size_t)t2 * 2 + 1], 2.f), 1.f);
  float gx = __fadd_rn(__fadd_rn(__fmul_rn(u0x, bary0), __fmul_rn(u1x, bary1)), __fmul_rn(u2x, bary2));
  float gy = __fadd_rn(__fadd_rn(__fmul_rn(u0y, bary0), __fmul_rn(u1y, bary1)), __fmul_rn(u2y, bary2));
  o_vt[pix2] = gx; o_vt[pix2 + HW] = gy;
  float sx = __fsub_rn(__fdiv_rn(__fmul_rn(__fadd_rn(gx, 1.0f), (float)TW), 2.0f), 0.5f);
  float sy = __fsub_rn(__fdiv_rn(__fmul_rn(__fadd_rn(gy, 1.0f), (float)TH), 2.0f), 0.5f);
  float x0f = floorf(sx), y0f = floorf(sy);
  float wx = __fsub_rn(sx, x0f), wy = __fsub_rn(sy, y0f);
  float omx = __fsub_rn(1.0f, wx), omy = __fsub_rn(1.0f, wy);
  int x0 = (int)x0f, y0 = (int)y0f;
  int x1 = x0 + 1, y1 = y0 + 1;
  bool v00 = (x0 >= 0) && (x0 < TW) && (y0 >= 0) && (y0 < TH);
  bool v10 = (x1 >= 0) && (x1 < TW) && (y0 >= 0) && (y0 < TH);
  bool v01 = (x0 >= 0) && (x0 < TW) && (y1 >= 0) && (y1 < TH);
  bool v11 = (x1 >= 0) && (x1 < TW) && (y1 >= 0) && (y1 < TH);
  int x0c = min(max(x0, 0), TW - 1), x1c = min(max(x1, 0), TW - 1);
  int y0c = min(max(y0, 0), TH - 1), y1c = min(max(y1, 0), TH - 1);
  const float* tb = tex + (size_t)b * 3 * TH * TW;
  #pragma unroll
  for (int ch = 0; ch < 3; ++ch) {
    const float* tc = tb + (size_t)ch * TH * TW;
    float g00 = v00 ? tc[(size_t)y0c * TW + x0c] : 0.f;
    float g10 = v10 ? tc[(size_t)y0c * TW + x1c] : 0.f;
    float g01 = v01 ? tc[(size_t)y1c * TW + x0c] : 0.f;
    float g11 = v11 ? tc[(size_t)y1c * TW + x1c] : 0.f;
    float r = __fmul_rn(__fmul_rn(g00, omx), omy);
    r = __fadd_rn(r, __fmul_rn(__fmul_rn(g10, wx), omy));
    r = __fadd_rn(r, __fmul_rn(__fmul_rn(g01, omx), wy));
    r = __fadd_rn(r, __fmul_rn(__fmul_rn(g11, wx), wy));
    o_img[pix3 + (size_t)ch * HW] = r;
  }
}

extern "C" void kernel_launch(void* const* d_in, const int* in_sizes, int n_in,
                              void* d_out, int out_size, void* d_ws, size_t ws_size,
                              hipStream_t stream) {
  const float* verts = (const float*)d_in[0];
  const float* tex   = (const float*)d_in[1];
  const float* Km    = (const float*)d_in[2];
  const float* Rt    = (const float*)d_in[3];
  const float* vt    = (const float*)d_in[4];
  const int*   vi    = (const int*)d_in[5];
  const int*   vti   = (const int*)d_in[6];

  int B = in_sizes[2] / 9;
  int V = in_sizes[0] / (3 * B);
  int F = in_sizes[5] / 3;
  long texhw = (long)in_sizes[1] / (B * 3);
  int TH = (int)(sqrt((double)texhw) + 0.5);
  int TW = TH;
  const int HW = H_ * W_;

  float* out = (float*)d_out;
  float* o_img   = out;
  float* o_depth = o_img + (size_t)B * 3 * HW;
  float* o_vpix  = o_depth + (size_t)B * HW;
  float* o_vt    = o_vpix + (size_t)B * V * 3;
  float* o_idx   = o_vt + (size_t)B * 2 * HW;
  float* o_bary  = o_idx + (size_t)B * HW;
  float* o_mask  = o_bary + (size_t)B * 3 * HW;

  size_t f4Bytes   = (size_t)B * F * 16;
  size_t listBytes = (size_t)B * NBAND * F * 16;
  size_t cntBytes  = (size_t)B * NBAND * NB * 4;
  size_t bstBytes  = (size_t)B * NBAND * (NB + 1) * 4;
  size_t need = 9 * f4Bytes + listBytes + 2 * cntBytes + bstBytes + 64;

  if (ws_size >= need) {
    char* w = (char*)d_ws;
    float4* sA    = (float4*)w;  w += f4Bytes;
    float4* sB4   = (float4*)w;  w += f4Bytes;
    float4* sC    = (float4*)w;  w += f4Bytes;
    float4* sZ1   = (float4*)w;  w += f4Bytes;
    float4* sE1   = (float4*)w;  w += f4Bytes;
    float4* sE2   = (float4*)w;  w += f4Bytes;
    float4* sUV12 = (float4*)w;  w += f4Bytes;
    float4* sUV2  = (float4*)w;  w += f4Bytes;
    float4* meta  = (float4*)w;  w += f4Bytes;
    uint4*  list  = (uint4*)w;   w += listBytes;
    int*    cnt   = (int*)w;     w += cntBytes;
    int*    bcur  = (int*)w;     w += cntBytes;
    int*    bst   = (int*)w;     w += bstBytes;
    unsigned* minmax = (unsigned*)w;

    int ninit = B * NBAND * NB;
    k_init<<<(ninit + 255) / 256, 256, 0, stream>>>(cnt, bcur, ninit, minmax);
    k_transform<<<(B * V + 255) / 256, 256, 0, stream>>>(verts, Km, Rt, o_vpix, minmax, B, V);
    k_faceprep<<<(B * F + 255) / 256, 256, 0, stream>>>(o_vpix, vi, vti, vt,
                                                        sA, sB4, sC, sZ1, sE1, sE2, sUV12, sUV2,
                                                        meta, minmax, cnt, B, V, F);
    k_bandscan<<<B * NBAND, NB, 0, stream>>>(cnt, bst);
    k_scatter<<<(B * F + 255) / 256, 256, 0, stream>>>(meta, bst, bcur, list, B, F);
    dim3 rg(W_ / 64, H_, B);
    k_raster_band<<<rg, 64 * ILV, 0, stream>>>(list, bst, sA, sB4, sC, sZ1, o_idx, B, F);
    k_render_rec<<<(B * HW + 255) / 256, 256, 0, stream>>>(sA, sE1, sE2, sZ1, sUV12, sUV2,
                                                           tex, o_idx,
                                                           o_img, o_depth, o_vt, o_bary, o_mask,
                                                           B, F, TH, TW);
  } else {
    k_transform<<<(B * V + 255) / 256, 256, 0, stream>>>(verts, Km, Rt, o_vpix,
                                                         (unsigned*)nullptr, B, V);
    k_raster_direct<<<(B * HW + 255) / 256, 256, 0, stream>>>(o_vpix, vi, o_idx, B, V, F);
    k_render<<<(B * HW + 255) / 256, 256, 0, stream>>>(o_vpix, vi, vti, vt, tex, o_idx,
                                                       o_img, o_depth, o_vt, o_bary, o_mask,
                                                       B, V, F, TH, TW);
  }
}

// Round 11
// 367.054 us; speedup vs baseline: 1.0367x; 1.0367x over previous
//
#include <hip/hip_runtime.h>
#include <cmath>

#define H_ 256
#define W_ 256
#define NB 256           // zmin buckets
#define BANDSH 3         // log2(band height): 8-row bands
#define NBAND (H_ >> BANDSH)   // 32
#define ILV 4            // face-subset waves per tile block
#define INITKEY 0x7f800000FFFFFFFFull

__device__ inline unsigned fkey(float f) {
  unsigned u = __float_as_uint(f);
  return (u & 0x80000000u) ? ~u : (u | 0x80000000u);
}
__device__ inline float unfkey(unsigned k) {
  return (k & 0x80000000u) ? __uint_as_float(k & 0x7fffffffu) : __uint_as_float(~k);
}

__device__ inline int zbucket(float zmin, float zlo, float scale) {
  int bkt = 0;
  if (zmin == zmin) bkt = min(NB - 1, max(0, (int)((zmin - zlo) * scale)));
  return bkt;
}

// ---------------- transform (+ vertex-z minmax for bucket range) ----------------
__global__ void k_transform(const float* __restrict__ verts, const float* __restrict__ Km,
                            const float* __restrict__ Rt, float* __restrict__ vpix,
                            unsigned* __restrict__ minmax, int B, int V) {
  int i = blockIdx.x * blockDim.x + threadIdx.x;
  unsigned kmin = 0xFFFFFFFFu, kmax = 0u;
  if (i < B * V) {
    int b = i / V;
    float x = verts[(size_t)i * 3 + 0], y = verts[(size_t)i * 3 + 1], z = verts[(size_t)i * 3 + 2];
    const float* R = Rt + (size_t)b * 12;
    float cx = __fadd_rn(__fadd_rn(__fadd_rn(__fmul_rn(R[0], x), __fmul_rn(R[1], y)), __fmul_rn(R[2], z)), R[3]);
    float cy = __fadd_rn(__fadd_rn(__fadd_rn(__fmul_rn(R[4], x), __fmul_rn(R[5], y)), __fmul_rn(R[6], z)), R[7]);
    float cz = __fadd_rn(__fadd_rn(__fadd_rn(__fmul_rn(R[8], x), __fmul_rn(R[9], y)), __fmul_rn(R[10], z)), R[11]);
    const float* Kb = Km + (size_t)b * 9;
    float px = __fadd_rn(__fadd_rn(__fmul_rn(Kb[0], cx), __fmul_rn(Kb[1], cy)), __fmul_rn(Kb[2], cz));
    float py = __fadd_rn(__fadd_rn(__fmul_rn(Kb[3], cx), __fmul_rn(Kb[4], cy)), __fmul_rn(Kb[5], cz));
    vpix[(size_t)i * 3 + 0] = __fdiv_rn(px, cz);
    vpix[(size_t)i * 3 + 1] = __fdiv_rn(py, cz);
    vpix[(size_t)i * 3 + 2] = cz;
    if (minmax && cz == cz) { kmin = fkey(cz); kmax = kmin; }
  }
  if (minmax) {
    #pragma unroll
    for (int m = 32; m >= 1; m >>= 1) {
      kmin = min(kmin, (unsigned)__shfl_xor((int)kmin, m));
      kmax = max(kmax, (unsigned)__shfl_xor((int)kmax, m));
    }
    if ((threadIdx.x & 63) == 0) {
      atomicMin(&minmax[0], kmin);
      atomicMax(&minmax[1], kmax);
    }
  }
}

// ---------------- init (runs before transform: minmax must be ready) ----------------
__global__ void k_init(int* __restrict__ cnt, int* __restrict__ bcur, int n,
                       unsigned* __restrict__ minmax) {
  int i = blockIdx.x * blockDim.x + threadIdx.x;
  if (i < n) { cnt[i] = 0; bcur[i] = 0; }
  if (i == 0) { minmax[0] = 0xFFFFFFFFu; minmax[1] = 0u; }
}

// ---------------- per-face precompute + fused band-bucket hist ----------------
// meta = {zmin, packbits(segmask|ylo<<8|yhi<<16), bkt_bits, floorval}; invalid: pack=0
__global__ void k_faceprep(const float* __restrict__ vpix, const int* __restrict__ vi,
                           const int* __restrict__ vti, const float* __restrict__ vt,
                           float4* __restrict__ sA, float4* __restrict__ sB4,
                           float4* __restrict__ sC, float4* __restrict__ sZ1,
                           float4* __restrict__ sE1, float4* __restrict__ sE2,
                           float4* __restrict__ sUV12, float4* __restrict__ sUV2,
                           float4* __restrict__ meta, const unsigned* __restrict__ minmax,
                           int* __restrict__ cnt, int B, int V, int F) {
  int i = blockIdx.x * blockDim.x + threadIdx.x;
  if (i >= B * F) return;
  int b = i / F, f = i - b * F;
  int i0 = vi[f * 3 + 0], i1 = vi[f * 3 + 1], i2 = vi[f * 3 + 2];
  const float* base = vpix + (size_t)b * V * 3;
  float ax = base[(size_t)i0 * 3], ay = base[(size_t)i0 * 3 + 1], az = base[(size_t)i0 * 3 + 2];
  float bx = base[(size_t)i1 * 3], by = base[(size_t)i1 * 3 + 1], bz = base[(size_t)i1 * 3 + 2];
  float cx = base[(size_t)i2 * 3], cy = base[(size_t)i2 * 3 + 1], cz = base[(size_t)i2 * 3 + 2];
  float e0x = __fsub_rn(cx, bx), e0y = __fsub_rn(cy, by);
  float e1x = __fsub_rn(ax, cx), e1y = __fsub_rn(ay, cy);
  float e2x = __fsub_rn(bx, ax), e2y = __fsub_rn(by, ay);
  float area = __fsub_rn(__fmul_rn(e2x, __fsub_rn(cy, ay)), __fmul_rn(e2y, __fsub_rn(cx, ax)));
  float s = (area > 0.f) ? 1.f : ((area < 0.f) ? -1.f : 0.f);
  bool nz = fabsf(area) > 1e-8f;
  bool zv = (az > 0.f) && (bz > 0.f) && (cz > 0.f);
  float sp = (nz && zv) ? s : __uint_as_float(0x7fc00000u);  // NaN: invalid
  float ar = nz ? area : 1.0f;
  float zmin = fminf(az, fminf(bz, cz));
  // raster records (sp-prefolded edges: IEEE-exact for sp=+-1; NaN -> inside=false)
  sA[i]  = make_float4(ax, ay, bx, by);
  sB4[i] = make_float4(cx, cy, __fmul_rn(sp, e0x), __fmul_rn(sp, e0y));
  sC[i]  = make_float4(__fmul_rn(sp, e1x), __fmul_rn(sp, e1y),
                       __fmul_rn(sp, e2x), __fmul_rn(sp, e2y));
  sZ1[i] = make_float4(az, bz, cz, __fmul_rn(sp, ar));
  // render records (RAW edges — identical bits to inline recompute)
  sE1[i] = make_float4(cx, cy, e0x, e0y);
  sE2[i] = make_float4(e1x, e1y, e2x, e2y);
  int t0 = vti[f * 3], t1 = vti[f * 3 + 1], t2 = vti[f * 3 + 2];
  float u0x = __fsub_rn(__fmul_rn(vt[(size_t)t0 * 2], 2.f), 1.f);
  float u0y = __fsub_rn(__fmul_rn(vt[(size_t)t0 * 2 + 1], 2.f), 1.f);
  float u1x = __fsub_rn(__fmul_rn(vt[(size_t)t1 * 2], 2.f), 1.f);
  float u1y = __fsub_rn(__fmul_rn(vt[(size_t)t1 * 2 + 1], 2.f), 1.f);
  float u2x = __fsub_rn(__fmul_rn(vt[(size_t)t2 * 2], 2.f), 1.f);
  float u2y = __fsub_rn(__fmul_rn(vt[(size_t)t2 * 2 + 1], 2.f), 1.f);
  sUV12[i] = make_float4(u0x, u0y, u1x, u1y);
  sUV2[i]  = make_float4(u2x, u2y, 0.f, 0.f);
  // integer pixel bbox (conservative-exact at pixel centers) -> packed cull word
  unsigned pack = 0u;   // 0 = invalid (empty segmask)
  int bkt = 0; float floorval = 0.f;
  float zlo = unfkey(minmax[0]), zhi = unfkey(minmax[1]);
  float rng = fmaxf(zhi - zlo, 1e-12f);
  float scale = (float)NB / rng;
  if (sp == sp) {
    float minx = fminf(ax, fminf(bx, cx)), maxx = fmaxf(ax, fmaxf(bx, cx));
    float miny = fminf(ay, fminf(by, cy)), maxy = fmaxf(ay, fmaxf(by, cy));
    int xl = (int)ceilf(fmaxf(fminf(minx - 0.5f, 1e9f), -1e9f));
    int xh = (int)floorf(fmaxf(fminf(maxx - 0.5f, 1e9f), -1e9f));
    int yl = (int)ceilf(fmaxf(fminf(miny - 0.5f, 1e9f), -1e9f));
    int yh = (int)floorf(fmaxf(fminf(maxy - 0.5f, 1e9f), -1e9f));
    if (!(xl > xh || yl > yh || xh < 0 || xl > W_ - 1 || yh < 0 || yl > H_ - 1)) {
      int xlo = max(xl, 0), xhi = min(xh, W_ - 1);
      int ylo = max(yl, 0), yhi = min(yh, H_ - 1);
      unsigned segmask = (((1u << ((xhi >> 6) + 1)) - 1u) & ~((1u << (xlo >> 6)) - 1u)) & 0xFu;
      pack = segmask | ((unsigned)ylo << 8) | ((unsigned)yhi << 16);
      bkt = zbucket(zmin, zlo, scale);
      floorval = zlo + (float)bkt * (rng / (float)NB);
      for (int band = (ylo >> BANDSH); band <= (yhi >> BANDSH); ++band)
        atomicAdd(&cnt[(b * NBAND + band) * NB + bkt], 1);
    }
  }
  meta[i] = make_float4(zmin, __uint_as_float(pack), __int_as_float(bkt), floorval);
}

// per-(band) exclusive prefix over buckets; bstart[row][NB] = total length
__global__ void k_bandscan(const int* __restrict__ cnt, int* __restrict__ bstart) {
  __shared__ int sh[NB];
  int rowi = blockIdx.x;
  int t = threadIdx.x;
  sh[t] = cnt[rowi * NB + t];
  __syncthreads();
  int self = sh[t];
  for (int ofs = 1; ofs < NB; ofs <<= 1) {
    int u = (t >= ofs) ? sh[t - ofs] : 0;
    __syncthreads();
    sh[t] += u;
    __syncthreads();
  }
  bstart[rowi * (NB + 1) + t] = sh[t] - self;
  if (t == NB - 1) bstart[rowi * (NB + 1) + NB] = sh[t];
}

// ---------------- fill band lists: entry = {pack, fid, zmin, zfloor} ----------------
__global__ void k_scatter(const float4* __restrict__ meta,
                          const int* __restrict__ bstart, int* __restrict__ bcur,
                          uint4* __restrict__ list, int B, int F) {
  int i = blockIdx.x * blockDim.x + threadIdx.x;
  if (i >= B * F) return;
  int b = i / F, f = i - b * F;
  float4 m = meta[i];
  unsigned pack = __float_as_uint(m.y);
  if ((pack & 0xFu) == 0u) return;  // invalid / off-screen
  int bkt = __float_as_int(m.z);
  uint4 ent = make_uint4(pack, (unsigned)f, __float_as_uint(m.x), __float_as_uint(m.w));
  int ylo = (int)((pack >> 8) & 255u), yhi = (int)((pack >> 16) & 255u);
  for (int band = (ylo >> BANDSH); band <= (yhi >> BANDSH); ++band) {
    int rowi = b * NBAND + band;
    int slot = bstart[rowi * (NB + 1) + bkt] + atomicAdd(&bcur[rowi * NB + bkt], 1);
    list[(size_t)rowi * F + slot] = ent;
  }
}

// ---------------- band rasterizer (R9: scalarized entry, 1-deep prefetch) ----------------
__global__ __launch_bounds__(64 * ILV) void k_raster_band(const uint4* __restrict__ list,
                                                          const int* __restrict__ bstart,
                                                          const float4* __restrict__ sA,
                                                          const float4* __restrict__ sB4,
                                                          const float4* __restrict__ sC,
                                                          const float4* __restrict__ sZ1,
                                                          float* __restrict__ o_idx,
                                                          int B, int F) {
  int seg = blockIdx.x;
  int y   = blockIdx.y;
  int b   = blockIdx.z;
  int tid = threadIdx.x;
  int w = tid >> 6, lane = tid & 63;
  __shared__ unsigned long long sk[64];
  if (tid < 64) sk[tid] = INITKEY;
  __syncthreads();
  int rowi = b * NBAND + (y >> BANDSH);
  int len = bstart[rowi * (NB + 1) + NB];
  const uint4* L = list + (size_t)rowi * F;
  size_t fb = (size_t)b * F;
  float px = seg * 64 + lane + 0.5f, py = y + 0.5f;
  unsigned long long bestkey = INITKEY;
  float bestz = INFINITY;
  int it = 0;
  int pos = w;
  uint4 e = (pos < len) ? L[pos] : make_uint4(0u, 0u, 0u, 0x7f800000u);
  while (pos < len) {
    int nxt = pos + ILV;
    uint4 en = L[(nxt < len) ? nxt : (len - 1)];  // meta needed unconditionally -> prefetch safe
    // scalarize the wave-uniform entry -> scalar branches, scalar record loads
    unsigned pack = __builtin_amdgcn_readfirstlane(e.x);
    int      fid  = __builtin_amdgcn_readfirstlane((int)e.y);
    float    zmn  = __uint_as_float(__builtin_amdgcn_readfirstlane(e.z));
    float    zfl  = __uint_as_float(__builtin_amdgcn_readfirstlane(e.w));
    // break: bucket floor lower-bounds zmin of this and all later entries (bucket-ascending)
    float floor0 = __fmul_rn(zfl, 0.9999f) - 1e-5f;  // margin: never skips a tie
    if (__all(floor0 > bestz)) break;
    ++it;
    if ((it & 7) == 0) {  // periodic cross-wave exchange via LDS
      unsigned long long old = atomicMin(&sk[lane], bestkey);
      if (old < bestkey) { bestkey = old; bestz = __uint_as_float((unsigned)(bestkey >> 32)); }
    }
    bool cull = !((pack >> seg) & 1u) ||
                (y < (int)((pack >> 8) & 255u)) || (y > (int)((pack >> 16) & 255u));
    if (!cull) {
      float4 a0 = sA[fb + fid];
      float4 a1 = sB4[fb + fid];
      float4 a2 = sC[fb + fid];
      // t_i == w_i * sp bit-exactly (sp pre-folded; -0>=0 true, NaN false)
      float t0 = __fsub_rn(__fmul_rn(a1.z, __fsub_rn(py, a0.w)), __fmul_rn(a1.w, __fsub_rn(px, a0.z)));
      float t1 = __fsub_rn(__fmul_rn(a2.x, __fsub_rn(py, a1.y)), __fmul_rn(a2.y, __fsub_rn(px, a1.x)));
      float t2 = __fsub_rn(__fmul_rn(a2.z, __fsub_rn(py, a0.y)), __fmul_rn(a2.w, __fsub_rn(px, a0.x)));
      bool inside = (t0 >= 0.f) && (t1 >= 0.f) && (t2 >= 0.f);
      // divide-skip: zmin*0.9999 > bestz provably can't beat or tie
      if (inside && !(__fmul_rn(zmn, 0.9999f) > bestz)) {
        float4 zz = sZ1[fb + fid];   // rare path only
        float u0 = __fdiv_rn(__fdiv_rn(t0, zz.w), zz.x);
        float u1 = __fdiv_rn(__fdiv_rn(t1, zz.w), zz.y);
        float u2 = __fdiv_rn(__fdiv_rn(t2, zz.w), zz.z);
        float invz = __fadd_rn(__fadd_rn(u0, u1), u2);
        if (invz > 0.f) {
          float z = __fdiv_rn(1.0f, fmaxf(invz, 1e-12f));
          unsigned long long ck = ((unsigned long long)__float_as_uint(z) << 32) | (unsigned)fid;
          if (ck < bestkey) {
            bestkey = ck; bestz = z;
            atomicMin(&sk[lane], ck);  // push so other waves see it
          }
        }
      }
    }
    pos = nxt;
    e = en;
  }
  atomicMin(&sk[lane], bestkey);
  __syncthreads();
  if (tid < 64) {
    unsigned long long k = sk[tid];
    unsigned zb = (unsigned)(k >> 32);
    o_idx[(size_t)b * (H_ * W_) + (size_t)y * W_ + seg * 64 + tid] =
        (zb >= 0x7f800000u) ? -1.0f : (float)(int)(unsigned)(k & 0xffffffffu);
  }
}

// ---------------- last-resort rasterizer (no workspace) ----------------
__global__ void k_raster_direct(const float* __restrict__ vpix, const int* __restrict__ vi,
                                float* __restrict__ idxout, int B, int V, int F) {
  int p = blockIdx.x * blockDim.x + threadIdx.x;
  if (p >= B * H_ * W_) return;
  int b = p / (H_ * W_); int pid = p - b * (H_ * W_);
  float px = (pid & (W_ - 1)) + 0.5f, py = (pid >> 8) + 0.5f;
  const float* base = vpix + (size_t)b * V * 3;
  float bestz = INFINITY; int besti = -1;
  for (int f = 0; f < F; ++f) {
    int i0 = vi[f * 3], i1 = vi[f * 3 + 1], i2 = vi[f * 3 + 2];
    float ax = base[(size_t)i0 * 3], ay = base[(size_t)i0 * 3 + 1], za = base[(size_t)i0 * 3 + 2];
    float bx = base[(size_t)i1 * 3], by = base[(size_t)i1 * 3 + 1], zb = base[(size_t)i1 * 3 + 2];
    float cx = base[(size_t)i2 * 3], cy = base[(size_t)i2 * 3 + 1], zc = base[(size_t)i2 * 3 + 2];
    float e0x = __fsub_rn(cx, bx), e0y = __fsub_rn(cy, by);
    float e1x = __fsub_rn(ax, cx), e1y = __fsub_rn(ay, cy);
    float e2x = __fsub_rn(bx, ax), e2y = __fsub_rn(by, ay);
    float area = __fsub_rn(__fmul_rn(e2x, __fsub_rn(cy, ay)), __fmul_rn(e2y, __fsub_rn(cx, ax)));
    float s = (area > 0.f) ? 1.f : ((area < 0.f) ? -1.f : 0.f);
    bool nz = fabsf(area) > 1e-8f;
    bool zv = (za > 0.f) && (zb > 0.f) && (zc > 0.f);
    float sp = (nz && zv) ? s : __uint_as_float(0x7fc00000u);
    float ar = nz ? area : 1.0f;
    float w0 = __fsub_rn(__fmul_rn(e0x, __fsub_rn(py, by)), __fmul_rn(e0y, __fsub_rn(px, bx)));
    float w1 = __fsub_rn(__fmul_rn(e1x, __fsub_rn(py, cy)), __fmul_rn(e1y, __fsub_rn(px, cx)));
    float w2 = __fsub_rn(__fmul_rn(e2x, __fsub_rn(py, ay)), __fmul_rn(e2y, __fsub_rn(px, ax)));
    bool inside = (__fmul_rn(w0, sp) >= 0.f) && (__fmul_rn(w1, sp) >= 0.f) && (__fmul_rn(w2, sp) >= 0.f);
    if (inside) {
      float invz = __fadd_rn(__fadd_rn(__fdiv_rn(__fdiv_rn(w0, ar), za),
                                       __fdiv_rn(__fdiv_rn(w1, ar), zb)),
                             __fdiv_rn(__fdiv_rn(w2, ar), zc));
      if (invz > 0.f) {
        float z = __fdiv_rn(1.0f, fmaxf(invz, 1e-12f));
        if (z < bestz) { bestz = z; besti = f; }
      }
    }
  }
  idxout[p] = (float)besti;
}

// ---------------- render from face records (6 float4 gathers + tex) ----------------
__global__ __launch_bounds__(256) void k_render_rec(const float4* __restrict__ sA,
                                                    const float4* __restrict__ sE1,
                                                    const float4* __restrict__ sE2,
                                                    const float4* __restrict__ sZ1,
                                                    const float4* __restrict__ sUV12,
                                                    const float4* __restrict__ sUV2,
                                                    const float* __restrict__ tex,
                                                    const float* __restrict__ idxin,
                                                    float* __restrict__ o_img, float* __restrict__ o_depth,
                                                    float* __restrict__ o_vt, float* __restrict__ o_bary,
                                                    float* __restrict__ o_mask,
                                                    int B, int F, int TH, int TW) {
  int p = blockIdx.x * blockDim.x + threadIdx.x;
  if (p >= B * H_ * W_) return;
  int HW = H_ * W_;
  int b = p / HW; int pid = p - b * HW;
  int y = pid >> 8, x = pid & (W_ - 1);
  int idx = (int)idxin[p];
  size_t pix2 = (size_t)b * 2 * HW + pid;
  size_t pix3 = (size_t)b * 3 * HW + pid;
  if (idx < 0) {
    o_depth[p] = 0.f; o_mask[p] = 0.f;
    o_vt[pix2] = 0.f; o_vt[pix2 + HW] = 0.f;
    o_bary[pix3] = 0.f; o_bary[pix3 + HW] = 0.f; o_bary[pix3 + 2 * HW] = 0.f;
    o_img[pix3] = 0.f; o_img[pix3 + HW] = 0.f; o_img[pix3 + 2 * HW] = 0.f;
    return;
  }
  size_t gp = (size_t)b * F + idx;
  float4 a0 = sA[gp];    // ax,ay,bx,by
  float4 e1 = sE1[gp];   // cx,cy,e0x,e0y (raw)
  float4 e2 = sE2[gp];   // e1x,e1y,e2x,e2y (raw)
  float4 zz = sZ1[gp];   // az,bz,cz,-
  float4 uv = sUV12[gp];
  float4 uv2 = sUV2[gp];
  float ptx = x + 0.5f, pty = y + 0.5f;
  float w0 = __fsub_rn(__fmul_rn(e1.z, __fsub_rn(pty, a0.w)), __fmul_rn(e1.w, __fsub_rn(ptx, a0.z)));
  float w1 = __fsub_rn(__fmul_rn(e2.x, __fsub_rn(pty, e1.y)), __fmul_rn(e2.y, __fsub_rn(ptx, e1.x)));
  float w2 = __fsub_rn(__fmul_rn(e2.z, __fsub_rn(pty, a0.y)), __fmul_rn(e2.w, __fsub_rn(ptx, a0.x)));
  float area = __fadd_rn(__fadd_rn(w0, w1), w2);
  float ar = (fabsf(area) > 1e-8f) ? area : 1.0f;
  float f0 = __fdiv_rn(__fdiv_rn(w0, ar), fmaxf(zz.x, 1e-8f));
  float f1 = __fdiv_rn(__fdiv_rn(w1, ar), fmaxf(zz.y, 1e-8f));
  float f2 = __fdiv_rn(__fdiv_rn(w2, ar), fmaxf(zz.z, 1e-8f));
  float invz = __fadd_rn(__fadd_rn(f0, f1), f2);
  float invz_s = (fabsf(invz) > 1e-12f) ? invz : 1.0f;
  float depth = __fdiv_rn(1.0f, invz_s);
  float bary0 = __fdiv_rn(f0, invz_s);
  float bary1 = __fdiv_rn(f1, invz_s);
  float bary2 = __fdiv_rn(f2, invz_s);
  o_depth[p] = depth; o_mask[p] = 1.0f;
  o_bary[pix3] = bary0; o_bary[pix3 + HW] = bary1; o_bary[pix3 + 2 * HW] = bary2;
  float gx = __fadd_rn(__fadd_rn(__fmul_rn(uv.x, bary0), __fmul_rn(uv.z, bary1)), __fmul_rn(uv2.x, bary2));
  float gy = __fadd_rn(__fadd_rn(__fmul_rn(uv.y, bary0), __fmul_rn(uv.w, bary1)), __fmul_rn(uv2.y, bary2));
  o_vt[pix2] = gx; o_vt[pix2 + HW] = gy;
  float sx = __fsub_rn(__fdiv_rn(__fmul_rn(__fadd_rn(gx, 1.0f), (float)TW), 2.0f), 0.5f);
  float sy = __fsub_rn(__fdiv_rn(__fmul_rn(__fadd_rn(gy, 1.0f), (float)TH), 2.0f), 0.5f);
  float x0f = floorf(sx), y0f = floorf(sy);
  float wx = __fsub_rn(sx, x0f), wy = __fsub_rn(sy, y0f);
  float omx = __fsub_rn(1.0f, wx), omy = __fsub_rn(1.0f, wy);
  int x0 = (int)x0f, y0 = (int)y0f;
  int x1 = x0 + 1, y1 = y0 + 1;
  bool v00 = (x0 >= 0) && (x0 < TW) && (y0 >= 0) && (y0 < TH);
  bool v10 = (x1 >= 0) && (x1 < TW) && (y0 >= 0) && (y0 < TH);
  bool v01 = (x0 >= 0) && (x0 < TW) && (y1 >= 0) && (y1 < TH);
  bool v11 = (x1 >= 0) && (x1 < TW) && (y1 >= 0) && (y1 < TH);
  int x0c = min(max(x0, 0), TW - 1), x1c = min(max(x1, 0), TW - 1);
  int y0c = min(max(y0, 0), TH - 1), y1c = min(max(y1, 0), TH - 1);
  const float* tb = tex + (size_t)b * 3 * TH * TW;
  #pragma unroll
  for (int ch = 0; ch < 3; ++ch) {
    const float* tc = tb + (size_t)ch * TH * TW;
    float g00 = v00 ? tc[(size_t)y0c * TW + x0c] : 0.f;
    float g10 = v10 ? tc[(size_t)y0c * TW + x1c] : 0.f;
    float g01 = v01 ? tc[(size_t)y1c * TW + x0c] : 0.f;
    float g11 = v11 ? tc[(size_t)y1c * TW + x1c] : 0.f;
    float r = __fmul_rn(__fmul_rn(g00, omx), omy);
    r = __fadd_rn(r, __fmul_rn(__fmul_rn(g10, wx), omy));
    r = __fadd_rn(r, __fmul_rn(__fmul_rn(g01, omx), wy));
    r = __fadd_rn(r, __fmul_rn(__fmul_rn(g11, wx), wy));
    o_img[pix3 + (size_t)ch * HW] = r;
  }
}

// ---------------- fallback render (per-pixel gathers, no records) ----------------
__global__ __launch_bounds__(256) void k_render(const float* __restrict__ vpix, const int* __restrict__ vi,
                                                const int* __restrict__ vti, const float* __restrict__ vt,
                                                const float* __restrict__ tex, const float* __restrict__ idxin,
                                                float* __restrict__ o_img, float* __restrict__ o_depth,
                                                float* __restrict__ o_vt, float* __restrict__ o_bary,
                                                float* __restrict__ o_mask,
                                                int B, int V, int F, int TH, int TW) {
  int p = blockIdx.x * blockDim.x + threadIdx.x;
  if (p >= B * H_ * W_) return;
  int HW = H_ * W_;
  int b = p / HW; int pid = p - b * HW;
  int y = pid >> 8, x = pid & (W_ - 1);
  int idx = (int)idxin[p];
  size_t pix2 = (size_t)b * 2 * HW + pid;
  size_t pix3 = (size_t)b * 3 * HW + pid;
  if (idx < 0) {
    o_depth[p] = 0.f; o_mask[p] = 0.f;
    o_vt[pix2] = 0.f; o_vt[pix2 + HW] = 0.f;
    o_bary[pix3] = 0.f; o_bary[pix3 + HW] = 0.f; o_bary[pix3 + 2 * HW] = 0.f;
    o_img[pix3] = 0.f; o_img[pix3 + HW] = 0.f; o_img[pix3 + 2 * HW] = 0.f;
    return;
  }
  const float* base = vpix + (size_t)b * V * 3;
  int i0 = vi[idx * 3], i1 = vi[idx * 3 + 1], i2 = vi[idx * 3 + 2];
  float ax = base[(size_t)i0 * 3], ay = base[(size_t)i0 * 3 + 1], az = base[(size_t)i0 * 3 + 2];
  float bx = base[(size_t)i1 * 3], by = base[(size_t)i1 * 3 + 1], bz = base[(size_t)i1 * 3 + 2];
  float cx = base[(size_t)i2 * 3], cy = base[(size_t)i2 * 3 + 1], cz = base[(size_t)i2 * 3 + 2];
  float ptx = x + 0.5f, pty = y + 0.5f;
  float w0 = __fsub_rn(__fmul_rn(__fsub_rn(cx, bx), __fsub_rn(pty, by)),
                       __fmul_rn(__fsub_rn(cy, by), __fsub_rn(ptx, bx)));
  float w1 = __fsub_rn(__fmul_rn(__fsub_rn(ax, cx), __fsub_rn(pty, cy)),
                       __fmul_rn(__fsub_rn(ay, cy), __fsub_rn(ptx, cx)));
  float w2 = __fsub_rn(__fmul_rn(__fsub_rn(bx, ax), __fsub_rn(pty, ay)),
                       __fmul_rn(__fsub_rn(by, ay), __fsub_rn(ptx, ax)));
  float area = __fadd_rn(__fadd_rn(w0, w1), w2);
  float ar = (fabsf(area) > 1e-8f) ? area : 1.0f;
  float f0 = __fdiv_rn(__fdiv_rn(w0, ar), fmaxf(az, 1e-8f));
  float f1 = __fdiv_rn(__fdiv_rn(w1, ar), fmaxf(bz, 1e-8f));
  float f2 = __fdiv_rn(__fdiv_rn(w2, ar), fmaxf(cz, 1e-8f));
  float invz = __fadd_rn(__fadd_rn(f0, f1), f2);
  float invz_s = (fabsf(invz) > 1e-12f) ? invz : 1.0f;
  float depth = __fdiv_rn(1.0f, invz_s);
  float bary0 = __fdiv_rn(f0, invz_s);
  float bary1 = __fdiv_rn(f1, invz_s);
  float bary2 = __fdiv_rn(f2, invz_s);
  o_depth[p] = depth; o_mask[p] = 1.0f;
  o_bary[pix3] = bary0; o_bary[pix3 + HW] = bary1; o_bary[pix3 + 2 * HW] = bary2;
  int t0 = vti[idx * 3], t1 = vti[idx * 3 + 1], t2 = vti[idx * 3 + 2];
  float u0x = __fsub_rn(__fmul_rn(vt[(size_t)t0 * 2], 2.f), 1.f);
  float u0y = __fsub_rn(__fmul_rn(vt[(size_t)t0 * 2 + 1], 2.f), 1.f);
  float u1x = __fsub_rn(__fmul_rn(vt[(size_t)t1 * 2], 2.f), 1.f);
  float u1y = __fsub_rn(__fmul_rn(vt[(size_t)t1 * 2 + 1], 2.f), 1.f);
  float u2x = __fsub_rn(__fmul_rn(vt[(size_t)t2 * 2], 2.f), 1.f);
  float u2y = __fsub_rn(__fmul_rn(vt[(size_t)t2 * 2 + 1], 2.f), 1.f);
  float gx = __fadd_rn(__fadd_rn(__fmul_rn(u0x, bary0), __fmul_rn(u1x, bary1)), __fmul_rn(u2x, bary2));
  float gy = __fadd_rn(__fadd_rn(__fmul_rn(u0y, bary0), __fmul_rn(u1y, bary1)), __fmul_rn(u2y, bary2));
  o_vt[pix2] = gx; o_vt[pix2 + HW] = gy;
  float sx = __fsub_rn(__fdiv_rn(__fmul_rn(__fadd_rn(gx, 1.0f), (float)TW), 2.0f), 0.5f);
  float sy = __fsub_rn(__fdiv_rn(__fmul_rn(__fadd_rn(gy, 1.0f), (float)TH), 2.0f), 0.5f);
  float x0f = floorf(sx), y0f = floorf(sy);
  float wx = __fsub_rn(sx, x0f), wy = __fsub_rn(sy, y0f);
  float omx = __fsub_rn(1.0f, wx), omy = __fsub_rn(1.0f, wy);
  int x0 = (int)x0f, y0 = (int)y0f;
  int x1 = x0 + 1, y1 = y0 + 1;
  bool v00 = (x0 >= 0) && (x0 < TW) && (y0 >= 0) && (y0 < TH);
  bool v10 = (x1 >= 0) && (x1 < TW) && (y0 >= 0) && (y0 < TH);
  bool v01 = (x0 >= 0) && (x0 < TW) && (y1 >= 0) && (y1 < TH);
  bool v11 = (x1 >= 0) && (x1 < TW) && (y1 >= 0) && (y1 < TH);
  int x0c = min(max(x0, 0), TW - 1), x1c = min(max(x1, 0), TW - 1);
  int y0c = min(max(y0, 0), TH - 1), y1c = min(max(y1, 0), TH - 1);
  const float* tb = tex + (size_t)b * 3 * TH * TW;
  #pragma unroll
  for (int ch = 0; ch < 3; ++ch) {
    const float* tc = tb + (size_t)ch * TH * TW;
    float g00 = v00 ? tc[(size_t)y0c * TW + x0c] : 0.f;
    float g10 = v10 ? tc[(size_t)y0c * TW + x1c] : 0.f;
    float g01 = v01 ? tc[(size_t)y1c * TW + x0c] : 0.f;
    float g11 = v11 ? tc[(size_t)y1c * TW + x1c] : 0.f;
    float r = __fmul_rn(__fmul_rn(g00, omx), omy);
    r = __fadd_rn(r, __fmul_rn(__fmul_rn(g10, wx), omy));
    r = __fadd_rn(r, __fmul_rn(__fmul_rn(g01, omx), wy));
    r = __fadd_rn(r, __fmul_rn(__fmul_rn(g11, wx), wy));
    o_img[pix3 + (size_t)ch * HW] = r;
  }
}

extern "C" void kernel_launch(void* const* d_in, const int* in_sizes, int n_in,
                              void* d_out, int out_size, void* d_ws, size_t ws_size,
                              hipStream_t stream) {
  const float* verts = (const float*)d_in[0];
  const float* tex   = (const float*)d_in[1];
  const float* Km    = (const float*)d_in[2];
  const float* Rt    = (const float*)d_in[3];
  const float* vt    = (const float*)d_in[4];
  const int*   vi    = (const int*)d_in[5];
  const int*   vti   = (const int*)d_in[6];

  int B = in_sizes[2] / 9;
  int V = in_sizes[0] / (3 * B);
  int F = in_sizes[5] / 3;
  long texhw = (long)in_sizes[1] / (B * 3);
  int TH = (int)(sqrt((double)texhw) + 0.5);
  int TW = TH;
  const int HW = H_ * W_;

  float* out = (float*)d_out;
  float* o_img   = out;
  float* o_depth = o_img + (size_t)B * 3 * HW;
  float* o_vpix  = o_depth + (size_t)B * HW;
  float* o_vt    = o_vpix + (size_t)B * V * 3;
  float* o_idx   = o_vt + (size_t)B * 2 * HW;
  float* o_bary  = o_idx + (size_t)B * HW;
  float* o_mask  = o_bary + (size_t)B * 3 * HW;

  size_t f4Bytes   = (size_t)B * F * 16;
  size_t listBytes = (size_t)B * NBAND * F * 16;
  size_t cntBytes  = (size_t)B * NBAND * NB * 4;
  size_t bstBytes  = (size_t)B * NBAND * (NB + 1) * 4;
  size_t need = 9 * f4Bytes + listBytes + 2 * cntBytes + bstBytes + 64;

  if (ws_size >= need) {
    char* w = (char*)d_ws;
    float4* sA    = (float4*)w;  w += f4Bytes;
    float4* sB4   = (float4*)w;  w += f4Bytes;
    float4* sC    = (float4*)w;  w += f4Bytes;
    float4* sZ1   = (float4*)w;  w += f4Bytes;
    float4* sE1   = (float4*)w;  w += f4Bytes;
    float4* sE2   = (float4*)w;  w += f4Bytes;
    float4* sUV12 = (float4*)w;  w += f4Bytes;
    float4* sUV2  = (float4*)w;  w += f4Bytes;
    float4* meta  = (float4*)w;  w += f4Bytes;
    uint4*  list  = (uint4*)w;   w += listBytes;
    int*    cnt   = (int*)w;     w += cntBytes;
    int*    bcur  = (int*)w;     w += cntBytes;
    int*    bst   = (int*)w;     w += bstBytes;
    unsigned* minmax = (unsigned*)w;

    int ninit = B * NBAND * NB;
    k_init<<<(ninit + 255) / 256, 256, 0, stream>>>(cnt, bcur, ninit, minmax);
    k_transform<<<(B * V + 255) / 256, 256, 0, stream>>>(verts, Km, Rt, o_vpix, minmax, B, V);
    k_faceprep<<<(B * F + 255) / 256, 256, 0, stream>>>(o_vpix, vi, vti, vt,
                                                        sA, sB4, sC, sZ1, sE1, sE2, sUV12, sUV2,
                                                        meta, minmax, cnt, B, V, F);
    k_bandscan<<<B * NBAND, NB, 0, stream>>>(cnt, bst);
    k_scatter<<<(B * F + 255) / 256, 256, 0, stream>>>(meta, bst, bcur, list, B, F);
    dim3 rg(W_ / 64, H_, B);
    k_raster_band<<<rg, 64 * ILV, 0, stream>>>(list, bst, sA, sB4, sC, sZ1, o_idx, B, F);
    k_render_rec<<<(B * HW + 255) / 256, 256, 0, stream>>>(sA, sE1, sE2, sZ1, sUV12, sUV2,
                                                           tex, o_idx,
                                                           o_img, o_depth, o_vt, o_bary, o_mask,
                                                           B, F, TH, TW);
  } else {
    k_transform<<<(B * V + 255) / 256, 256, 0, stream>>>(verts, Km, Rt, o_vpix,
                                                         (unsigned*)nullptr, B, V);
    k_raster_direct<<<(B * HW + 255) / 256, 256, 0, stream>>>(o_vpix, vi, o_idx, B, V, F);
    k_render<<<(B * HW + 255) / 256, 256, 0, stream>>>(o_vpix, vi, vti, vt, tex, o_idx,
                                                       o_img, o_depth, o_vt, o_bary, o_mask,
                                                       B, V, F, TH, TW);
  }
}